// Round 8
// baseline (164.216 us; speedup 1.0000x reference)
//
#include <hip/hip_runtime.h>
#include <type_traits>

#define RES_ 0.16f
#define XMIN_ -51.2f
#define YMIN_ -51.2f
#define EPS_ 1e-5f
#define NEG_ -1000000000.0f

#define WPB 4  // waves per block

typedef _Float16 f16x8 __attribute__((ext_vector_type(8)));
typedef _Float16 f16x4 __attribute__((ext_vector_type(4)));
typedef _Float16 f16x2 __attribute__((ext_vector_type(2)));
typedef float f32x4 __attribute__((ext_vector_type(4)));

union F8u { f16x8 v; f16x2 h[4]; };
union F4u { f16x4 v; f16x2 h[2]; };

static __device__ __forceinline__ f16x2 pkrtz(float a, float b) {
    return __builtin_bit_cast(f16x2, __builtin_amdgcn_cvt_pkrtz(a, b));
}

static __device__ __forceinline__ f16x2 relu2(f16x2 x) {
#if __has_builtin(__builtin_elementwise_max)
    const f16x2 z2 = (f16x2)(_Float16)0.f;
    return __builtin_elementwise_max(x, z2);   // v_pk_max_f16
#else
    f16x2 r;
    r[0] = x[0] > (_Float16)0.f ? x[0] : (_Float16)0.f;
    r[1] = x[1] > (_Float16)0.f ? x[1] : (_Float16)0.f;
    return r;
#endif
}

static __device__ __forceinline__ float fast_rcp(float x) {
#if __has_builtin(__builtin_amdgcn_rcpf)
    return __builtin_amdgcn_rcpf(x);
#else
    return 1.0f / x;
#endif
}

// DPP row_ror add — pure-VALU cross-lane sum within each 16-lane row.
template <int CTRL>
static __device__ __forceinline__ float dpp_ror_add(float x) {
    int r = __builtin_amdgcn_update_dpp(0, __float_as_int(x), CTRL, 0xf, 0xf, true);
    return x + __int_as_float(r);
}

// xor16 / xor32 max via gfx950 VALU cross-lane swaps (zero DS traffic).
static __device__ __forceinline__ float xmax16(float x) {
    float a = x, b = x;
    asm("v_permlane16_swap_b32 %0, %1" : "+v"(a), "+v"(b));
    return fmaxf(a, b);
}
static __device__ __forceinline__ float xmax32(float x) {
    float a = x, b = x;
    asm("v_permlane32_swap_b32 %0, %1" : "+v"(a), "+v"(b));
    return fmaxf(a, b);
}

// two b128 LDS reads + wait, one volatile asm block (r19; rule-18-safe:
// consuming MFMAs use the asm OUTPUTS -> true data dep).
template <int IDX0, int IDX1>
static __device__ __forceinline__ void lds_read2_b128(unsigned base, f16x8& a, f16x8& b) {
    asm volatile("ds_read_b128 %0, %2 offset:%c3\n\t"
                 "ds_read_b128 %1, %2 offset:%c4\n\t"
                 "s_waitcnt lgkmcnt(0)"
                 : "=v"(a), "=v"(b)
                 : "v"(base), "i"(IDX0 * 1024), "i"(IDX1 * 1024));
}

// NOTE (r11): zero-LDS dataflow — layer-1 transposed (W1^T @ feat^T); its MFMA
// C-output IS layer-2's A-operand under W2 k-row perm c=32kt+16(j>>2)+4q+(j&3).
// NOTE (occupancy model, r14/r15/r18/r19): residency is budget/demand-set.
// (256,4)=4 waves, (256,5)+LDS-bw2=5 waves (r19, occ 33->37) — but dur FLAT.
// More TLP does not convert to throughput; waves are stalled on intra-wave
// dependency chains (vector-issue only ~55%, MFMA 18%, HBM 11%: nothing
// saturated). In-order execution means only SOURCE-LEVEL interleaving can
// fill those stalls.
// NOTE (r19 flaw, fixed r21): body lgkmcnt(0) waits ALSO drained the s_load
// prefetches (lgkm counts DS+SMEM). Fix: p no longer readfirstlane'd ->
// npts/coords prefetch become VECTOR loads (vmcnt) -> lgkm is DS-only.
// NOTE (r21, this round): X/Y skewed pipeline at CONSTANT occupancy
// (unlike r18): X = pack+L1+repack (VALU-heavy), Y = L2 chains+fold+epi
// (MFMA/DS-heavy). Iteration i runs X(p+1) interleaved with Y(p) in one
// straight-line region. Extra live state ~16 regs (av2 frags), (256,4).
// NOTE (r18 PIN): full pillar-pairing at (256,3) regressed. This differs:
// occupancy held, stage-level skew, not 2x state.
// Tripwires: WRITE_SIZE==25000KB, absmax==0.5, VGPR<=~80.
__global__ __launch_bounds__(256, 4) void pfn_kernel(
    const float* __restrict__ pillars,
    const int* __restrict__ coords,
    const int* __restrict__ npts_arr,
    const float* __restrict__ W1, const float* __restrict__ b1,
    const float* __restrict__ g1, const float* __restrict__ beta1,
    const float* __restrict__ m1, const float* __restrict__ v1,
    const float* __restrict__ W2, const float* __restrict__ b2,
    const float* __restrict__ g2, const float* __restrict__ beta2,
    const float* __restrict__ m2, const float* __restrict__ v2,
    float* __restrict__ out, int P)
{
    const int tid  = threadIdx.x;
    const int wave = tid >> 6;
    const int lane = tid & 63;
    const int quad = lane >> 4;
    const int col  = lane & 15;

    // [kt*4+nt][lane][8 halfs] — 8KB. Identical for all waves/blocks.
    __shared__ _Float16 bw2s[8][64][8];

    // ---- cooperative bw2 preamble: wave w computes nt=w slice (kt=0,1) ----
    {
        const int nt = wave;
        const int n0 = nt * 16 + col;
        const float a2 = g2[n0] * rsqrtf(v2[n0] + EPS_);
#pragma unroll
        for (int kt = 0; kt < 2; ++kt) {
            F8u w;
#pragma unroll
            for (int j = 0; j < 8; ++j) {
                const int c = 32 * kt + 16 * (j >> 2) + 4 * quad + (j & 3);
                w.v[j] = (_Float16)(a2 * W2[c * 64 + n0]);
            }
            *(f16x8*)&bw2s[kt * 4 + nt][lane][0] = w.v;
        }
    }

    // ---- W1^T as layer-1 A-frags (K padded 9->16), BN1 folded (per wave) ----
    f16x4 aw1[4];
#pragma unroll
    for (int mt = 0; mt < 4; ++mt) {
        const int ch = mt * 16 + col;
        const float a1 = g1[ch] * rsqrtf(v1[ch] + EPS_);
        const float c1 = fmaf(a1, b1[ch] - m1[ch], beta1[ch]);
#pragma unroll
        for (int j = 0; j < 4; ++j) {
            const int k = quad * 4 + j;
            float w;
            if (k < 9)        w = a1 * W1[k * 64 + ch];
            else if (k == 9)  w = c1;                      // bias slot (feat=1.0)
            else if (k == 10) w = a1 * W1[6 * 64 + ch];    // z_mean slot (feat=-zm)
            else              w = 0.0f;
            aw1[mt][j] = (_Float16)w;
        }
    }
    const float c2own = fmaf(g2[lane] * rsqrtf(v2[lane] + EPS_),
                             b2[lane] - m2[lane], beta2[lane]);

    __syncthreads();   // bw2s ready (must precede any return)

    const unsigned bwbase = (unsigned)(size_t)&bw2s[0][lane][0];

    auto zreduce = [&](const float4& A, const float4& B, int n) -> float {
        float zs = (col < n) ? A.z : 0.0f;
        zs += (16 + col < n) ? B.z : 0.0f;
        zs = dpp_ror_add<0x128>(zs);   // row_ror:8
        zs = dpp_ror_add<0x124>(zs);   // row_ror:4
        zs = dpp_ror_add<0x122>(zs);   // row_ror:2
        zs = dpp_ror_add<0x121>(zs);   // row_ror:1
        return zs * fast_rcp(fmaxf((float)n, 1.0f));
    };

    // ---- stage X: one 16-pt tile -> layer-2 A-frags (pack + 4 L1 + repack) --
    auto Xt = [&](const float4& pt, float xcv, float ycv, float zmv,
                  f16x8& o0, f16x8& o1) {
        const float xo = pt.x - xcv;
        const float yo = pt.y - ycv;
        const f16x2 c01 = pkrtz(pt.x, pt.y);
        const f16x2 c23 = pkrtz(pt.z, pt.w);
        const f16x2 c45 = pkrtz(xo, yo);
        const f16x2 c67 = pkrtz(pt.z, xo);
        const f16x2 c89 = pkrtz(yo, 1.0f);
        const f16x2 cab = pkrtz(-zmv, 0.0f);
        const f16x2 z2  = (f16x2)(_Float16)0.f;
        F4u u;
        u.h[0] = (quad == 0) ? c01 : (quad == 1) ? c45 : (quad == 2) ? c89 : z2;
        u.h[1] = (quad == 0) ? c23 : (quad == 1) ? c67 : (quad == 2) ? cab : z2;
        f32x4 a0c, a1c, a2c, a3c;
        const f32x4 zz = {0.f, 0.f, 0.f, 0.f};
        a0c = __builtin_amdgcn_mfma_f32_16x16x16f16(aw1[0], u.v, zz, 0, 0, 0);
        a1c = __builtin_amdgcn_mfma_f32_16x16x16f16(aw1[1], u.v, zz, 0, 0, 0);
        a2c = __builtin_amdgcn_mfma_f32_16x16x16f16(aw1[2], u.v, zz, 0, 0, 0);
        a3c = __builtin_amdgcn_mfma_f32_16x16x16f16(aw1[3], u.v, zz, 0, 0, 0);
        F8u w0, w1;
        w0.h[0] = relu2(pkrtz(a0c[0], a0c[1]));
        w0.h[1] = relu2(pkrtz(a0c[2], a0c[3]));
        w0.h[2] = relu2(pkrtz(a1c[0], a1c[1]));
        w0.h[3] = relu2(pkrtz(a1c[2], a1c[3]));
        w1.h[0] = relu2(pkrtz(a2c[0], a2c[1]));
        w1.h[1] = relu2(pkrtz(a2c[2], a2c[3]));
        w1.h[2] = relu2(pkrtz(a3c[0], a3c[1]));
        w1.h[3] = relu2(pkrtz(a3c[2], a3c[3]));
        o0 = w0.v;
        o1 = w1.v;
    };

    // ---- stage Y core: 4 nt chains for one tile (8 MFMA + DS), fold ----
    auto Yt = [&](const f16x8& a0, const f16x8& a1, const f32x4& cm,
                  float& h0, float& h1, float& h2, float& h3) {
        f16x8 b0, b1; f32x4 acc;
        lds_read2_b128<0, 4>(bwbase, b0, b1);
        acc = __builtin_amdgcn_mfma_f32_16x16x32_f16(a0, b0, cm, 0, 0, 0);
        acc = __builtin_amdgcn_mfma_f32_16x16x32_f16(a1, b1, acc, 0, 0, 0);
        h0 = fmaxf(fmaxf(h0, fmaxf(acc[0], acc[1])), fmaxf(acc[2], acc[3]));
        lds_read2_b128<1, 5>(bwbase, b0, b1);
        acc = __builtin_amdgcn_mfma_f32_16x16x32_f16(a0, b0, cm, 0, 0, 0);
        acc = __builtin_amdgcn_mfma_f32_16x16x32_f16(a1, b1, acc, 0, 0, 0);
        h1 = fmaxf(fmaxf(h1, fmaxf(acc[0], acc[1])), fmaxf(acc[2], acc[3]));
        lds_read2_b128<2, 6>(bwbase, b0, b1);
        acc = __builtin_amdgcn_mfma_f32_16x16x32_f16(a0, b0, cm, 0, 0, 0);
        acc = __builtin_amdgcn_mfma_f32_16x16x32_f16(a1, b1, acc, 0, 0, 0);
        h2 = fmaxf(fmaxf(h2, fmaxf(acc[0], acc[1])), fmaxf(acc[2], acc[3]));
        lds_read2_b128<3, 7>(bwbase, b0, b1);
        acc = __builtin_amdgcn_mfma_f32_16x16x32_f16(a0, b0, cm, 0, 0, 0);
        acc = __builtin_amdgcn_mfma_f32_16x16x32_f16(a1, b1, acc, 0, 0, 0);
        h3 = fmaxf(fmaxf(h3, fmaxf(acc[0], acc[1])), fmaxf(acc[2], acc[3]));
    };

    auto mkcm = [&](int npv, int tt) -> f32x4 {
        f32x4 cm;
#pragma unroll
        for (int r = 0; r < 4; ++r)
            cm[r] = (tt * 16 + quad * 4 + r < npv) ? 0.0f : NEG_;
        return cm;
    };

    auto epi = [&](float h0, float h1, float h2, float h3) -> float {
        const float e0 = xmax32(xmax16(h0));
        const float e1 = xmax32(xmax16(h1));
        const float e2 = xmax32(xmax16(h2));
        const float e3 = xmax32(xmax16(h3));
        const float r0 = (quad == 0) ? e0 : (quad == 1) ? e1 : (quad == 2) ? e2 : e3;
        return fmaxf(r0 + c2own, 0.0f);
    };

    const int nwaves = gridDim.x * WPB;
    // NOT readfirstlane'd (r21): keeps npts/coords loads on the VECTOR path
    // (vmcnt) so body lgkmcnt(0) waits are DS-only.
    int p = blockIdx.x * WPB + wave;
    if (p >= P) return;

    // ---- prologue: load + z + X for pillar 0 ----
    const float4* pb = (const float4*)(pillars + (size_t)p * 128);
    float4 cA = pb[col], cB = pb[16 + col];
    int np_c = npts_arr[p];
    int cy_c = coords[2 * p], cx_c = coords[2 * p + 1];
    np_c = np_c < 0 ? 0 : (np_c > 32 ? 32 : np_c);
    float zm_c = zreduce(cA, cB, np_c);
    f16x8 A0, A1, B0, B1;
    {
        const float xcc = ((float)cx_c + 0.5f) * RES_ + XMIN_;
        const float ycc = ((float)cy_c + 0.5f) * RES_ + YMIN_;
        Xt(cA, xcc, ycc, zm_c, A0, A1);
        if (__builtin_amdgcn_readfirstlane(np_c) > 16)
            Xt(cB, xcc, ycc, zm_c, B0, B1);
    }

    // ---- next pillar state ----
    int pn = p + nwaves;
    bool hn = pn < P;
    float4 nA{}, nB{};
    int np_n = 0, cy_n = 0, cx_n = 0;
    float zm_n = 0.0f;
    if (hn) {
        const float4* pbn = (const float4*)(pillars + (size_t)pn * 128);
        nA = pbn[col]; nB = pbn[16 + col];
        np_n = npts_arr[pn];
        cy_n = coords[2 * pn]; cx_n = coords[2 * pn + 1];
        np_n = np_n < 0 ? 0 : (np_n > 32 ? 32 : np_n);
        zm_n = zreduce(nA, nB, np_n);
    }

    while (true) {
        const int uc = __builtin_amdgcn_readfirstlane(np_c);

        if (!hn) {
            // ---- tail: Y(cur) only ----
            float res = NEG_;
            if (uc > 0) {
                float h0 = NEG_, h1 = NEG_, h2 = NEG_, h3 = NEG_;
                Yt(A0, A1, mkcm(np_c, 0), h0, h1, h2, h3);
                if (uc > 16)
                    Yt(B0, B1, mkcm(np_c, 1), h0, h1, h2, h3);
                res = epi(h0, h1, h2, h3);
            }
            out[(size_t)p * 64 + lane] = res;
            break;
        }

        // ---- prefetch nn (vector loads; vmcnt) ----
        const int pnn = pn + nwaves;
        const bool hnn = pnn < P;
        float4 nnA{}, nnB{};
        int np_nn = 0, cy_nn = 0, cx_nn = 0;
        if (hnn) {
            const float4* pbn = (const float4*)(pillars + (size_t)pnn * 128);
            nnA = pbn[col]; nnB = pbn[16 + col];
            np_nn = npts_arr[pnn];
            cy_nn = coords[2 * pnn]; cx_nn = coords[2 * pnn + 1];
        }

        const int un = __builtin_amdgcn_readfirstlane(np_n);
        const float xcn = ((float)cx_n + 0.5f) * RES_ + XMIN_;
        const float ycn = ((float)cy_n + 0.5f) * RES_ + YMIN_;

        f16x8 NA0, NA1, NB0, NB1;

        // ---- fused region: X(next) interleaved with Y(cur) ----
        auto yx = [&](auto MC) -> float {
            constexpr int m = decltype(MC)::value;
            Xt(nA, xcn, ycn, zm_n, NA0, NA1);            // X t0 (always)
            float h0 = NEG_, h1 = NEG_, h2 = NEG_, h3 = NEG_;
            if constexpr (m >= 1) {
                const f32x4 cm0 = mkcm(np_c, 0);
                Yt(A0, A1, cm0, h0, h1, h2, h3);          // Y t0
            }
            if (un > 16)
                Xt(nB, xcn, ycn, zm_n, NB0, NB1);        // X t1 (cond)
            if constexpr (m == 2) {
                const f32x4 cm1 = mkcm(np_c, 1);
                Yt(B0, B1, cm1, h0, h1, h2, h3);          // Y t1
            }
            if constexpr (m >= 1)
                return epi(h0, h1, h2, h3);
            else
                return NEG_;
        };

        float res;
        if (uc > 16)     res = yx(std::integral_constant<int, 2>{});
        else if (uc > 0) res = yx(std::integral_constant<int, 1>{});
        else             res = yx(std::integral_constant<int, 0>{});
        out[(size_t)p * 64 + lane] = res;

        // ---- z for nn (pure VALU; vmcnt wait lands here, covered by body) ----
        float zm_nn = 0.0f;
        if (hnn) {
            np_nn = np_nn < 0 ? 0 : (np_nn > 32 ? 32 : np_nn);
            zm_nn = zreduce(nnA, nnB, np_nn);
        }

        // ---- rotate ----
        p = pn; np_c = np_n;
        A0 = NA0; A1 = NA1;
        if (un > 16) { B0 = NB0; B1 = NB1; }
        pn = pnn; hn = hnn;
        nA = nnA; nB = nnB; np_n = np_nn; cy_n = cy_nn; cx_n = cx_nn;
        zm_n = zm_nn;
    }
}

extern "C" void kernel_launch(void* const* d_in, const int* in_sizes, int n_in,
                              void* d_out, int out_size, void* d_ws, size_t ws_size,
                              hipStream_t stream) {
    const float* pillars = (const float*)d_in[0];
    const int*   coords  = (const int*)d_in[1];
    const int*   npts    = (const int*)d_in[2];
    const float* W1      = (const float*)d_in[3];
    const float* b1      = (const float*)d_in[4];
    const float* g1      = (const float*)d_in[5];
    const float* beta1   = (const float*)d_in[6];
    const float* m1      = (const float*)d_in[7];
    const float* v1      = (const float*)d_in[8];
    const float* W2      = (const float*)d_in[9];
    const float* b2      = (const float*)d_in[10];
    const float* g2      = (const float*)d_in[11];
    const float* beta2   = (const float*)d_in[12];
    const float* m2      = (const float*)d_in[13];
    const float* v2      = (const float*)d_in[14];
    float* out           = (float*)d_out;

    const int P = in_sizes[2];
    // (256,4) + 1024 blocks: hold occupancy at 4 waves/SIMD (r18 showed 3
    // waves is worse; r19 showed 5 waves is not better). The experiment this
    // round is the X/Y skew, at constant residency.
    const int blocks = 1024;

    hipLaunchKernelGGL(pfn_kernel, dim3(blocks), dim3(256), 0, stream,
                       pillars, coords, npts, W1, b1, g1, beta1, m1, v1,
                       W2, b2, g2, beta2, m2, v2, out, P);
}

// Round 9
// 147.112 us; speedup vs baseline: 1.1163x; 1.1163x over previous
//
#include <hip/hip_runtime.h>
#include <type_traits>

#define RES_ 0.16f
#define XMIN_ -51.2f
#define YMIN_ -51.2f
#define EPS_ 1e-5f
#define NEG_ -1000000000.0f

#define WPB 4  // waves per block

typedef _Float16 f16x8 __attribute__((ext_vector_type(8)));
typedef _Float16 f16x4 __attribute__((ext_vector_type(4)));
typedef _Float16 f16x2 __attribute__((ext_vector_type(2)));
typedef float f32x4 __attribute__((ext_vector_type(4)));

union F8u { f16x8 v; f16x2 h[4]; };
union F4u { f16x4 v; f16x2 h[2]; };

// cvt_pkrtz returns __fp16x2 on this clang; launder to _Float16x2 (same bits)
static __device__ __forceinline__ f16x2 pkrtz(float a, float b) {
    return __builtin_bit_cast(f16x2, __builtin_amdgcn_cvt_pkrtz(a, b));
}

static __device__ __forceinline__ f16x2 relu2(f16x2 x) {
#if __has_builtin(__builtin_elementwise_max)
    const f16x2 z2 = (f16x2)(_Float16)0.f;
    return __builtin_elementwise_max(x, z2);   // v_pk_max_f16
#else
    f16x2 r;
    r[0] = x[0] > (_Float16)0.f ? x[0] : (_Float16)0.f;
    r[1] = x[1] > (_Float16)0.f ? x[1] : (_Float16)0.f;
    return r;
#endif
}

static __device__ __forceinline__ float fast_rcp(float x) {
#if __has_builtin(__builtin_amdgcn_rcpf)
    return __builtin_amdgcn_rcpf(x);   // v_rcp_f32, ~1ulp — fine at f16 downstream
#else
    return 1.0f / x;
#endif
}

// r22: single-instruction 3-input max (VOP3; gfx9+). clang does not reliably
// fuse nested fmaxf into v_max3_f32, so force it. Pure, no volatile.
static __device__ __forceinline__ float max3f(float a, float b, float c) {
    float d;
    asm("v_max3_f32 %0, %1, %2, %3" : "=v"(d) : "v"(a), "v"(b), "v"(c));
    return d;
}

// NOTE (r11): zero-LDS dataflow — layer-1 computed transposed (W1^T @ feat^T) so
// its MFMA C-output IS layer-2's A-operand under a W2 k-row permutation
// c(kt,quad,j)=32kt+16(j>>2)+4quad+(j&3). No LDS staging, no h1 round-trip.
// NOTE (ledger, r13..r21, per-dispatch us): r13 structure = 57.5 (BEST).
//  r14 (256,8): spill, 252. r15 grid 2048: 66. r16/17 DS->VALU: 59.
//  r18 pillar-pairing (256,3): 74, absmax 70.5. r19 bw2->LDS + 5 waves: 60.
//  r21 X/Y skew: 72.5, absmax 42.5. CONCLUSION: more TLP, more ILP, DS
//  elimination, and reg-demand reduction are ALL neutral-to-negative on this
//  body. The counters at the optimum (VALU 52%, MFMA 18%, HBM 11%, occ 33%)
//  describe a mixed issue/latency equilibrium; remaining lever = fewer
//  instructions on the SAME structure.
// NOTE (r22, this round): exact r13 revert (registers-resident bw2, shfl
//  reductions, (256,4), 1024 blocks) + instruction diet: v_max3_f32 fold
//  (4 fmax -> 2 max3 per nt) and pointer-bump addressing for prefetch/store.
// Tripwires: absmax==0.5, VGPR~56, WRITE_SIZE==25000KB.
__global__ __launch_bounds__(256, 4) void pfn_kernel(
    const float* __restrict__ pillars,
    const int* __restrict__ coords,
    const int* __restrict__ npts_arr,
    const float* __restrict__ W1, const float* __restrict__ b1,
    const float* __restrict__ g1, const float* __restrict__ beta1,
    const float* __restrict__ m1, const float* __restrict__ v1,
    const float* __restrict__ W2, const float* __restrict__ b2,
    const float* __restrict__ g2, const float* __restrict__ beta2,
    const float* __restrict__ m2, const float* __restrict__ v2,
    float* __restrict__ out, int P)
{
    const int tid  = threadIdx.x;
    const int wave = tid >> 6;
    const int lane = tid & 63;
    const int quad = lane >> 4;
    const int col  = lane & 15;

    // ---- W1^T as layer-1 A-frags (K padded 9->16), BN1 scale+bias+z folded ----
    // A[m = mtile*16+col (channel)][k = quad*4+j (feat slot)]
    // slots: {x,y,z,r,xo,yo,z,xo,yo, 1.0(bias), -z_mean(w6 again), 0...}
    f16x4 aw1[4];
#pragma unroll
    for (int mt = 0; mt < 4; ++mt) {
        const int ch = mt * 16 + col;
        const float a1 = g1[ch] * rsqrtf(v1[ch] + EPS_);
        const float c1 = fmaf(a1, b1[ch] - m1[ch], beta1[ch]);
#pragma unroll
        for (int j = 0; j < 4; ++j) {
            const int k = quad * 4 + j;
            float w;
            if (k < 9)        w = a1 * W1[k * 64 + ch];
            else if (k == 9)  w = c1;                      // bias slot (feat=1.0)
            else if (k == 10) w = a1 * W1[6 * 64 + ch];    // z_mean slot (feat=-zm)
            else              w = 0.0f;
            aw1[mt][j] = (_Float16)w;
        }
    }

    // ---- W2 (BN2-scale folded), k-rows permuted to match in-register h1 layout ----
    f16x8 bw2[2][4];
#pragma unroll
    for (int nt = 0; nt < 4; ++nt) {
        const int n0 = nt * 16 + col;
        const float a2 = g2[n0] * rsqrtf(v2[n0] + EPS_);
#pragma unroll
        for (int kt = 0; kt < 2; ++kt)
#pragma unroll
            for (int j = 0; j < 8; ++j) {
                const int c = 32 * kt + 16 * (j >> 2) + 4 * quad + (j & 3);
                bw2[kt][nt][j] = (_Float16)(a2 * W2[c * 64 + n0]);
            }
    }
    // lane's own output-channel bias (applied AFTER the row-max; max is shift-equivariant)
    const float c2own = fmaf(g2[lane] * rsqrtf(v2[lane] + EPS_),
                             b2[lane] - m2[lane], beta2[lane]);

    // z reduction: sum valid z over 16-col groups (quads replicate), mean via rcp
    auto zreduce = [&](const float4& A, const float4& B, int n) -> float {
        float zs = (col < n) ? A.z : 0.0f;
        zs += (16 + col < n) ? B.z : 0.0f;
#pragma unroll
        for (int off = 1; off <= 8; off <<= 1) zs += __shfl_xor(zs, off, 64);
        return zs * fast_rcp(fmaxf((float)n, 1.0f));
    };

    const int nwaves = gridDim.x * WPB;
    int p = __builtin_amdgcn_readfirstlane(blockIdx.x * WPB + wave);
    if (p >= P) return;

    // ---- r22: pointer-bump addressing (constant strides, no per-iter p*K) ----
    const float4* pb   = (const float4*)pillars + (size_t)p * 32;
    const int*    npp  = npts_arr + p;
    const int*    cpp  = coords + 2 * (size_t)p;
    float*        outp = out + (size_t)p * 64 + lane;
    const size_t  pb_step  = (size_t)nwaves * 32;   // float4 units
    const size_t  out_step = (size_t)nwaves * 64;

    // ---- preamble: load + z for pillar 0 ----
    float4 ptA = pb[col];
    float4 ptB = pb[16 + col];
    int np = npp[0];
    int cy = cpp[0], cx = cpp[1];
    np = np < 0 ? 0 : (np > 32 ? 32 : np);
    float z_cur = zreduce(ptA, ptB, np);

    while (true) {
        const int pn = p + nwaves;
        const bool has_next = pn < P;
        float4 ptAn, ptBn; int npn = 0, cyn = 0, cxn = 0;
        if (has_next) {                       // wave-uniform; issue loads early
            const float4* pbn = pb + pb_step;
            ptAn = pbn[col];
            ptBn = pbn[16 + col];
            npn = npp[nwaves];
            cyn = cpp[2 * (size_t)nwaves];
            cxn = cpp[2 * (size_t)nwaves + 1];
        }

        const int npu = __builtin_amdgcn_readfirstlane(np);
        const float xc = ((float)cx + 0.5f) * RES_ + XMIN_;
        const float yc = ((float)cy + 0.5f) * RES_ + YMIN_;
        const float z_mean = z_cur;

        // ================= pillar body (zero LDS) =================
        auto body = [&](auto MTC) -> float {
            constexpr int MT = decltype(MTC)::value;
            float hm4[4] = {NEG_, NEG_, NEG_, NEG_};

#pragma unroll
            for (int t = 0; t < MT; ++t) {
                const float4 pt = (t == 0) ? ptA : ptB;

                // ---- feat^T B-frag: B[k=quad*4+j][n=point col] ----
                const float xo = pt.x - xc;
                const float yo = pt.y - yc;
                const f16x2 c01 = pkrtz(pt.x, pt.y);       // quad0: x,y
                const f16x2 c23 = pkrtz(pt.z, pt.w);       // quad0: z,r
                const f16x2 c45 = pkrtz(xo, yo);           // quad1: xo,yo
                const f16x2 c67 = pkrtz(pt.z, xo);         // quad1: z(slot6), xo
                const f16x2 c89 = pkrtz(yo, 1.0f);         // quad2: yo, bias-1
                const f16x2 cab = pkrtz(-z_mean, 0.0f);    // quad2: -zm, 0
                const f16x2 z2  = (f16x2)(_Float16)0.f;
                F4u u;
                u.h[0] = (quad == 0) ? c01 : (quad == 1) ? c45 : (quad == 2) ? c89 : z2;
                u.h[1] = (quad == 0) ? c23 : (quad == 1) ? c67 : (quad == 2) ? cab : z2;
                const f16x4 bt = u.v;

                // ---- layer-1: 4 MFMAs, C=0 (bias+z in K-slots) ----
                f32x4 acc1[4];
                const f32x4 zz = {0.f, 0.f, 0.f, 0.f};
#pragma unroll
                for (int mt = 0; mt < 4; ++mt)
                    acc1[mt] = __builtin_amdgcn_mfma_f32_16x16x16f16(aw1[mt], bt, zz, 0, 0, 0);

                // ---- h1 relu + pack: layer-2 A-frags, pure in-lane ----
                f16x8 av2[2];
#pragma unroll
                for (int kt = 0; kt < 2; ++kt) {
                    F8u w;
                    w.h[0] = relu2(pkrtz(acc1[2 * kt][0],     acc1[2 * kt][1]));
                    w.h[1] = relu2(pkrtz(acc1[2 * kt][2],     acc1[2 * kt][3]));
                    w.h[2] = relu2(pkrtz(acc1[2 * kt + 1][0], acc1[2 * kt + 1][1]));
                    w.h[3] = relu2(pkrtz(acc1[2 * kt + 1][2], acc1[2 * kt + 1][3]));
                    av2[kt] = w.v;
                }

                // ---- row-mask as layer-2 C-init (free adds) ----
                f32x4 cm;
#pragma unroll
                for (int r = 0; r < 4; ++r)
                    cm[r] = (t * 16 + quad * 4 + r < np) ? 0.0f : NEG_;

                // ---- layer-2: stream per nt, fold into running max (max3) ----
#pragma unroll
                for (int nt = 0; nt < 4; ++nt) {
                    f32x4 acc = __builtin_amdgcn_mfma_f32_16x16x32_f16(av2[0], bw2[0][nt], cm, 0, 0, 0);
                    acc = __builtin_amdgcn_mfma_f32_16x16x32_f16(av2[1], bw2[1][nt], acc, 0, 0, 0);
                    hm4[nt] = max3f(hm4[nt], max3f(acc[0], acc[1], acc[2]), acc[3]);
                }
            }

            // ---- cross-quad max, select own channel, bias+relu ----
            float hmv[4];
#pragma unroll
            for (int nt = 0; nt < 4; ++nt) {
                float hm = hm4[nt];
                hm = fmaxf(hm, __shfl_xor(hm, 16, 64));
                hm = fmaxf(hm, __shfl_xor(hm, 32, 64));
                hmv[nt] = hm;
            }
            float r0 = (quad == 0) ? hmv[0] : (quad == 1) ? hmv[1] : (quad == 2) ? hmv[2] : hmv[3];
            return fmaxf(r0 + c2own, 0.0f);
        };

        float res;
        if (npu > 16)     res = body(std::integral_constant<int, 2>{});
        else if (npu > 0) res = body(std::integral_constant<int, 1>{});
        else              res = NEG_;
        *outp = res;

        if (!has_next) break;

        // ---- pipelined: z for NEXT pillar (shuffle chain overlaps MFMA drain) ----
        npn = npn < 0 ? 0 : (npn > 32 ? 32 : npn);
        z_cur = zreduce(ptAn, ptBn, npn);

        p = pn; ptA = ptAn; ptB = ptBn; np = npn; cy = cyn; cx = cxn;
        pb += pb_step; npp += nwaves; cpp += 2 * (size_t)nwaves; outp += out_step;
    }
}

extern "C" void kernel_launch(void* const* d_in, const int* in_sizes, int n_in,
                              void* d_out, int out_size, void* d_ws, size_t ws_size,
                              hipStream_t stream) {
    const float* pillars = (const float*)d_in[0];
    const int*   coords  = (const int*)d_in[1];
    const int*   npts    = (const int*)d_in[2];
    const float* W1      = (const float*)d_in[3];
    const float* b1      = (const float*)d_in[4];
    const float* g1      = (const float*)d_in[5];
    const float* beta1   = (const float*)d_in[6];
    const float* m1      = (const float*)d_in[7];
    const float* v1      = (const float*)d_in[8];
    const float* W2      = (const float*)d_in[9];
    const float* b2      = (const float*)d_in[10];
    const float* g2      = (const float*)d_in[11];
    const float* beta2   = (const float*)d_in[12];
    const float* m2      = (const float*)d_in[13];
    const float* v2      = (const float*)d_in[14];
    float* out           = (float*)d_out;

    const int P = in_sizes[2];
    // r13/r22: 1024 blocks (4 blocks/CU), (256,4). The r13 structure is the
    // measured optimum; this round changes only instruction count.
    const int blocks = 1024;

    hipLaunchKernelGGL(pfn_kernel, dim3(blocks), dim3(256), 0, stream,
                       pillars, coords, npts, W1, b1, g1, beta1, m1, v1,
                       W2, b2, g2, beta2, m2, v2, out, P);
}